// Round 1
// baseline (164.442 us; speedup 1.0000x reference)
//
#include <hip/hip_runtime.h>

// BlockDiagonalLinear hyperbolic layer, fused.
// out = gamma(row) * (x @ blockdiag(W)^T), with gamma computed analytically
// from ||x|| and ||x@W^T|| (expmap0 scale c folds into gamma).
//
// Layout: 512 WGs x 512 threads (8 waves). Each WG owns 16 rows.
//   Phase 1: load x (float4), per-row sumsq, bf16 -> LDS (XOR-swizzled).
//   Phase 2: 16x16x32 bf16 MFMA; wave w computes blocks {2w, 2w+1} for all
//            16 rows x 256 cols. B fragments read from bf16 W copy in d_ws
//            (L2-resident, 2 MiB).
//   Epilogue: per-row ||mx'||^2 reduce, gamma scalar pipeline, scale+store.

typedef __attribute__((ext_vector_type(8))) short short8;
typedef __attribute__((ext_vector_type(4))) float f32x4;

__device__ __forceinline__ ushort f2bf(float f) {
  uint u = __float_as_uint(f);
  return (ushort)((u + 0x7fffu + ((u >> 16) & 1u)) >> 16);  // RNE
}

__global__ __launch_bounds__(256) void wconv_kernel(const float* __restrict__ w,
                                                    ushort* __restrict__ wb) {
  int i = blockIdx.x * blockDim.x + threadIdx.x;  // 262144 float4s total
  float4 v = reinterpret_cast<const float4*>(w)[i];
  uint2 p;
  p.x = (uint)f2bf(v.x) | ((uint)f2bf(v.y) << 16);
  p.y = (uint)f2bf(v.z) | ((uint)f2bf(v.w) << 16);
  reinterpret_cast<uint2*>(wb)[i] = p;
}

template <bool WS>
__global__ __launch_bounds__(512, 2) void hyp_kernel(const float* __restrict__ x,
                                                     const float* __restrict__ wf,
                                                     const ushort* __restrict__ wb,
                                                     float* __restrict__ out) {
  __shared__ ushort hsm[16 * 4096];  // 128 KiB, XOR-swizzled bf16 x-tile
  __shared__ float ssx[16];          // per-row ||x||^2
  __shared__ float ssp[8][16];       // per-wave partial ||mx'||^2
  __shared__ float gam[16];          // per-row output scale

  const int tid = threadIdx.x;
  const int wid = tid >> 6;
  const int lane = tid & 63;
  const int g = lane >> 4;   // k-group for MFMA fragments
  const int q = lane & 15;   // row (A) / col (B) within fragment
  const size_t rowbase = (size_t)blockIdx.x * 16;

  // ---- Phase 1: x -> sumsq + bf16 LDS ----
  for (int r = 0; r < 2; ++r) {
    const int row = wid * 2 + r;
    const float4* xr = reinterpret_cast<const float4*>(x + (rowbase + row) * 4096);
    float ss = 0.f;
#pragma unroll
    for (int chunk = 0; chunk < 16; ++chunk) {
      float4 v = xr[chunk * 64 + lane];
      ss += v.x * v.x + v.y * v.y + v.z * v.z + v.w * v.w;
      uint2 p;
      p.x = (uint)f2bf(v.x) | ((uint)f2bf(v.y) << 16);
      p.y = (uint)f2bf(v.z) | ((uint)f2bf(v.w) << 16);
      uint byte = (uint)(row * 8192 + chunk * 512 + lane * 8);
      byte ^= (uint)((row & 7) << 4);  // swizzle: spread rows across banks
      *reinterpret_cast<uint2*>(reinterpret_cast<char*>(hsm) + byte) = p;
    }
#pragma unroll
    for (int m = 32; m; m >>= 1) ss += __shfl_xor(ss, m, 64);
    if (lane == 0) ssx[row] = ss;
  }
  __syncthreads();

  // ---- Phase 2: MFMA. wave wid -> blocks {2*wid, 2*wid+1} ----
  f32x4 acc[2][16];
#pragma unroll
  for (int bb = 0; bb < 2; ++bb)
#pragma unroll
    for (int nt = 0; nt < 16; ++nt) acc[bb][nt] = (f32x4){0.f, 0.f, 0.f, 0.f};

#pragma unroll
  for (int bb = 0; bb < 2; ++bb) {
    const int b = wid * 2 + bb;
    short8 afr[8];  // A fragments for this block: rows=q, k = b*256 + kf*32 + g*8 ..+7
#pragma unroll
    for (int kf = 0; kf < 8; ++kf) {
      uint byte = (uint)(q * 8192 + b * 512 + kf * 64 + g * 16);
      byte ^= (uint)((q & 7) << 4);
      afr[kf] = *reinterpret_cast<const short8*>(reinterpret_cast<const char*>(hsm) + byte);
    }
#pragma unroll
    for (int nt = 0; nt < 16; ++nt) {
      const size_t wrow = ((size_t)b << 16) + (size_t)(nt * 16 + q) * 256;
#pragma unroll
      for (int kf = 0; kf < 8; ++kf) {
        short8 bfr;  // B[k][n] = W[b][n][k]: contiguous in k -> 16B load
        if (WS) {
          bfr = *reinterpret_cast<const short8*>(wb + wrow + kf * 32 + g * 8);
        } else {
          const float* wp = wf + wrow + kf * 32 + g * 8;
          float4 w0 = *reinterpret_cast<const float4*>(wp);
          float4 w1 = *reinterpret_cast<const float4*>(wp + 4);
          bfr[0] = (short)f2bf(w0.x); bfr[1] = (short)f2bf(w0.y);
          bfr[2] = (short)f2bf(w0.z); bfr[3] = (short)f2bf(w0.w);
          bfr[4] = (short)f2bf(w1.x); bfr[5] = (short)f2bf(w1.y);
          bfr[6] = (short)f2bf(w1.z); bfr[7] = (short)f2bf(w1.w);
        }
        acc[bb][nt] = __builtin_amdgcn_mfma_f32_16x16x32_bf16(afr[kf], bfr, acc[bb][nt], 0, 0, 0);
      }
    }
  }

  // ---- Epilogue: per-row ||mx'||^2 ----
  float s0 = 0.f, s1 = 0.f, s2a = 0.f, s3 = 0.f;
#pragma unroll
  for (int bb = 0; bb < 2; ++bb)
#pragma unroll
    for (int nt = 0; nt < 16; ++nt) {
      f32x4 a = acc[bb][nt];
      s0 += a[0] * a[0];
      s1 += a[1] * a[1];
      s2a += a[2] * a[2];
      s3 += a[3] * a[3];
    }
#pragma unroll
  for (int m = 1; m < 16; m <<= 1) {  // reduce across the 16 q-lanes
    s0 += __shfl_xor(s0, m, 64);
    s1 += __shfl_xor(s1, m, 64);
    s2a += __shfl_xor(s2a, m, 64);
    s3 += __shfl_xor(s3, m, 64);
  }
  if (q == 0) {
    ssp[wid][g * 4 + 0] = s0;
    ssp[wid][g * 4 + 1] = s1;
    ssp[wid][g * 4 + 2] = s2a;
    ssp[wid][g * 4 + 3] = s3;
  }
  __syncthreads();

  if (tid < 16) {
    float s2 = 0.f;
#pragma unroll
    for (int w = 0; w < 8; ++w) s2 += ssp[w][tid];
    const float xnorm = sqrtf(ssx[tid]);
    const float un = fmaxf(xnorm, 1e-5f);
    const float a0 = 0.1f * un;
    const float th = tanhf(fminf(a0, 15.f));
    const float c = th / a0;             // h = c * x
    const float hn = th * (xnorm / a0);  // ||h||
    const float xn = fmaxf(hn, 1e-5f);
    const float sp = sqrtf(s2);          // ||mx'||
    float gt = 0.f;
    if (sp > 0.f) {
      const float s = c * sp;  // ||mx||
      const float xc = fminf(0.1f * xn, 1.f - 1e-5f);
      const float at = 0.5f * logf((1.f + xc) / (1.f - xc));  // artanh
      const float t = (s / xn) * at;
      const float tn = tanhf(fminf(t, 15.f));
      const float alpha = tn / (0.1f * s);  // res_c = alpha * mx
      const float rn = tn * 10.f;           // ||res_c||
      const float nrm = fmaxf(rn, 1e-5f);
      const float proj = (nrm > 9.99f) ? (9.99f / nrm) : 1.f;  // _project
      const float yn = fmaxf(rn * proj, 1e-5f);
      const float yc = fminf(0.1f * yn, 1.f - 1e-5f);
      const float at2 = 0.5f * logf((1.f + yc) / (1.f - yc));
      gt = c * alpha * proj * (at2 / (0.1f * yn));  // logmap0 + fold of c
    }
    gam[tid] = gt;
  }
  __syncthreads();

  // ---- Store: out = gamma(row) * mx' ----
  float gr[4];
#pragma unroll
  for (int j = 0; j < 4; ++j) gr[j] = gam[g * 4 + j];
  float* orow = out + rowbase * 4096;
#pragma unroll
  for (int bb = 0; bb < 2; ++bb) {
    const int b = wid * 2 + bb;
#pragma unroll
    for (int nt = 0; nt < 16; ++nt) {
      const int col = b * 256 + nt * 16 + q;
      f32x4 a = acc[bb][nt];
#pragma unroll
      for (int j = 0; j < 4; ++j) {
        orow[(size_t)(g * 4 + j) * 4096 + col] = gr[j] * a[j];
      }
    }
  }
}

extern "C" void kernel_launch(void* const* d_in, const int* in_sizes, int n_in,
                              void* d_out, int out_size, void* d_ws, size_t ws_size,
                              hipStream_t stream) {
  const float* x = (const float*)d_in[0];   // [4,2048,4096] f32
  const float* w = (const float*)d_in[1];   // [16,256,256] f32
  float* out = (float*)d_out;               // [4,2048,4096] f32

  const size_t wb_bytes = (size_t)16 * 256 * 256 * sizeof(ushort);  // 2 MiB
  if (ws_size >= wb_bytes) {
    ushort* wb = (ushort*)d_ws;
    wconv_kernel<<<1024, 256, 0, stream>>>(w, wb);
    hyp_kernel<true><<<512, 512, 0, stream>>>(x, w, wb, out);
  } else {
    hyp_kernel<false><<<512, 512, 0, stream>>>(x, w, nullptr, out);
  }
}